// Round 7
// baseline (80.523 us; speedup 1.0000x reference)
//
#include <hip/hip_runtime.h>

// QuantumLayer: 8-qubit, 4-layer VQC, state evolution entirely in registers.
// With STATE as MFMA A-operand and GATE as B, each pass's C-layout output is
// exactly the next pass's A-fragment (transpose absorbed by alternating the
// passive dimension u,l,u,l...). CNOTs 0-2 folded into H~ rows; CNOTs 4-6 (tau,
// linear) baked into G_R k-order + encoding lane labels; CNOT3 residual = lane
// swap n<->n^8 on odd-u registers = v_mov_dpp row_ror:8. LDS: 8KB sign-frag
// table + per-wave 8KB p-buffer for the measurement MFMAs.
// ROUND-7: r6 (ILP4, 2 waves/SIMD) showed static scheduling can't hide the
// MFMA->pack / readlane hazards (27us vs 5us issue model). Fix: occupancy.
// 128-VGPR cap (launch_bounds(256,4)) -> 4 blocks/CU -> 4 waves/SIMD; sign
// frags moved to LDS (-32 regs), ILP back to 2, i-loop rolled. Wave-level
// interleave hides all stall classes dynamically.

typedef _Float16 half8  __attribute__((ext_vector_type(8)));
typedef float    float4v __attribute__((ext_vector_type(4)));
typedef unsigned int uint2v __attribute__((ext_vector_type(2)));
typedef unsigned int uint4v __attribute__((ext_vector_type(4)));

#define MEMFENCE() __asm__ volatile("" ::: "memory")

__device__ __forceinline__ unsigned pk2(float a, float b) {
  auto v = __builtin_amdgcn_cvt_pkrtz(a, b);   // packed f32->f16x2, 1 instr
  return __builtin_bit_cast(unsigned, v);
}
__device__ __forceinline__ float rdlane(float v, int l) {
  return __builtin_bit_cast(float, __builtin_amdgcn_readlane(__builtin_bit_cast(int, v), l));
}
// lane n <- lane n^8 within each 16-lane row (row_ror:8)
__device__ __forceinline__ unsigned sw8u(unsigned v) {
  return (unsigned)__builtin_amdgcn_mov_dpp((int)v, 0x128, 0xf, 0xf, false);
}
__device__ __forceinline__ float sw8f(float v) {
  return __builtin_bit_cast(float,
      __builtin_amdgcn_mov_dpp(__builtin_bit_cast(int, v), 0x128, 0xf, 0xf, false));
}
__device__ __forceinline__ int tauf(int l) {   // CNOTs 4,5,6 on l (linear)
  int y = l ^ (((l >> 3) & 1) << 2);
  y ^= ((y >> 2) & 1) << 1;
  y ^= (y >> 1) & 1;
  return y;
}

__launch_bounds__(256, 4)
__global__ void qmain(const float* __restrict__ x, const float* __restrict__ w,
                      float* __restrict__ out) {
  // [0,8192) sign frags; [8192,40960) per-wave p-buffers (gate staging overlays)
  __shared__ __align__(16) unsigned char smem[40960];
  const int tid = threadIdx.x;
  const int lane = tid & 63, wv = tid >> 6;
  const int quad = lane >> 4, n = lane & 15;

  // ---- phase 0: wave wv builds layer wv's 4 gate B-frags into staging LDS ----
  {
    const int t = wv;
    int mr = n ^ ((n >> 1) & 1);            // P^-1(n): CNOTs 0,1,2 fold
    mr ^= ((mr >> 2) & 1) << 1;
    mr ^= ((mr >> 3) & 1) << 2;
    float cS[8], sS[8], zcS[8], zsS[8];
#pragma unroll
    for (int qq = 0; qq < 8; ++qq) {
      float th = w[(t * 8 + qq) * 2 + 0];
      float tz = w[(t * 8 + qq) * 2 + 1];
      __sincosf(0.5f * th, &sS[qq], &cS[qq]);
      __sincosf(0.5f * tz, &zsS[qq], &zcS[qq]);
    }
    union { _Float16 h[8]; half8 v; } bLR, bLI, bRR, bRI;
#pragma unroll
    for (int ci = 0; ci < 4; ++ci) {
      const int kp = quad * 4 + ci;          // k-pair index
      float hr = 1.f, hi = 0.f;              // G_L = H~[n][kp] = H[mr][kp]
#pragma unroll
      for (int j = 0; j < 4; ++j) {
        int rb = (mr >> (3 - j)) & 1, cb = (kp >> (3 - j)) & 1;
        float ryv = (rb == cb) ? cS[j] : (rb ? sS[j] : -sS[j]);
        float ar = zcS[j] * ryv;
        float ai = (rb ? zsS[j] : -zsS[j]) * ryv;
        float nr = hr * ar - hi * ai, ni = hr * ai + hi * ar;
        hr = nr; hi = ni;
      }
      bLR.h[2 * ci] = (_Float16)hr;  bLR.h[2 * ci + 1] = (_Float16)(-hi);
      bLI.h[2 * ci] = (_Float16)hi;  bLI.h[2 * ci + 1] = (_Float16)hr;
      int yk = tauf(kp);                     // G_R = L~[n][tau(kp)]
      float wr = 1.f, wi = 0.f;
#pragma unroll
      for (int j = 0; j < 4; ++j) {
        int rb = (n >> (3 - j)) & 1, cb = (yk >> (3 - j)) & 1;
        float ryv = (rb == cb) ? cS[4 + j] : (rb ? sS[4 + j] : -sS[4 + j]);
        float ar = zcS[4 + j] * ryv;
        float ai = (rb ? zsS[4 + j] : -zsS[4 + j]) * ryv;
        float nr = wr * ar - wi * ai, ni = wr * ai + wi * ar;
        wr = nr; wi = ni;
      }
      bRR.h[2 * ci] = (_Float16)wr;  bRR.h[2 * ci + 1] = (_Float16)(-wi);
      bRI.h[2 * ci] = (_Float16)wi;  bRI.h[2 * ci + 1] = (_Float16)wr;
    }
    half8* FB = (half8*)(smem + 8192);
    FB[(t * 4 + 0) * 64 + lane] = bLR.v;
    FB[(t * 4 + 1) * 64 + lane] = bLI.v;
    FB[(t * 4 + 2) * 64 + lane] = bRR.v;
    FB[(t * 4 + 3) * 64 + lane] = bRI.v;
  }
  __syncthreads();
  half8 BLR[4], BLI[4], BRR[4], BRI[4];
#pragma unroll
  for (int t = 0; t < 4; ++t) {
    const half8* FB = (const half8*)(smem + 8192);
    BLR[t] = FB[(t * 4 + 0) * 64 + lane];
    BLI[t] = FB[(t * 4 + 1) * 64 + lane];
    BRR[t] = FB[(t * 4 + 2) * 64 + lane];
    BRI[t] = FB[(t * 4 + 3) * 64 + lane];
  }
  // ---- sign fragments -> LDS [0,8192) (all waves write identical values) ----
#pragma unroll
  for (int c = 0; c < 8; ++c) {
    union { _Float16 h[8]; half8 v; } sg;
#pragma unroll
    for (int jj = 0; jj < 8; ++jj) {
      int u = (quad & 1) * 8 + jj;
      int y = tauf(2 * c + (quad >> 1));
      float sv = 0.f;
      if (n < 8) {
        int bit = (n < 4) ? ((u >> (3 - n)) & 1) : ((y >> (7 - n)) & 1);
        sv = bit ? -1.f : 1.f;
      }
      sg.h[jj] = (_Float16)sv;
    }
    *(half8*)(smem + c * 1024 + lane * 16) = sg.v;
  }
  __syncthreads();   // p-buffers may now overlay the staging region

  unsigned char* smp = smem + 8192 + wv * 8192;
  const unsigned pWg = (unsigned)(2 * n + (quad >> 1));   // p-write granule
  const unsigned pWlo = (unsigned)((quad & 1) * 8);
  const int e0 = (blockIdx.x * 4 + wv) * 16;
  const float4v zz = {0.f, 0.f, 0.f, 0.f};
  const int ytau = tauf(n);     // lane's true l label

  // angle loads + sincos for the wave's 16 elements (128 floats)
  const float* xp = x + (size_t)e0 * 8;
  float xA = xp[lane], xB = xp[64 + lane];
  float CA, SA, CB, SB;
  __sincosf(0.5f * xA, &SA, &CA);
  __sincosf(0.5f * xB, &SB, &CB);

  for (int i = 0; i < 8; ++i) {   // ILP2: elements e = 2i+h, h=0..1
    uint4v st[2];
#pragma unroll
    for (int h = 0; h < 2; ++h) {
      const int e = 2 * i + h;
      const float cs = (i < 4) ? CA : CB;    // uniform select
      const float sn = (i < 4) ? SA : SB;
      const int lb = (e & 7) * 8;            // uniform (SGPR) readlane base
      float cq[8], sq[8];
#pragma unroll
      for (int q = 0; q < 8; ++q) { cq[q] = rdlane(cs, lb + q); sq[q] = rdlane(sn, lb + q); }
      float f0 = (quad & 2) ? sq[0] : cq[0];
      float f1 = (quad & 1) ? sq[1] : cq[1];
      float f4 = (ytau & 8) ? sq[4] : cq[4];
      float f5 = (ytau & 4) ? sq[5] : cq[5];
      float f6 = (ytau & 2) ? sq[6] : cq[6];
      float f7 = (ytau & 1) ? sq[7] : cq[7];
      float pb = f0 * f1 * f4 * f5 * f6 * f7;
      st[h][0] = pk2(pb * cq[2] * cq[3], 0.f);
      st[h][1] = pk2(pb * cq[2] * sq[3], 0.f);
      st[h][2] = pk2(pb * sq[2] * cq[3], 0.f);
      st[h][3] = pk2(pb * sq[2] * sq[3], 0.f);
    }

#pragma unroll
    for (int t = 0; t < 4; ++t) {
      // pass L: D1 = S^T * G_L  (8 independent MFMAs across 2 chains)
      float4v xr[2], xi[2];
#pragma unroll
      for (int c = 0; c < 2; ++c) {
        half8 A = __builtin_bit_cast(half8, st[c]);
        xr[c] = __builtin_amdgcn_mfma_f32_16x16x32_f16(A, BLR[t], zz, 0, 0, 0);
        xi[c] = __builtin_amdgcn_mfma_f32_16x16x32_f16(A, BLI[t], zz, 0, 0, 0);
      }
      uint4v X[2];
#pragma unroll
      for (int c = 0; c < 2; ++c) {
        X[c][0] = pk2(xr[c][0], xi[c][0]);
        X[c][1] = pk2(xr[c][1], xi[c][1]);
        X[c][2] = pk2(xr[c][2], xi[c][2]);
        X[c][3] = pk2(xr[c][3], xi[c][3]);
      }
      // pass R: D2 = X * G_R
      float4v yr[2], yi[2];
#pragma unroll
      for (int c = 0; c < 2; ++c) {
        half8 XA = __builtin_bit_cast(half8, X[c]);
        yr[c] = __builtin_amdgcn_mfma_f32_16x16x32_f16(XA, BRR[t], zz, 0, 0, 0);
        yi[c] = __builtin_amdgcn_mfma_f32_16x16x32_f16(XA, BRI[t], zz, 0, 0, 0);
      }
      if (t < 3) {
        // CNOT fix: odd-u regs swap lanes n<->n^8 (tau deferred to gates)
#pragma unroll
        for (int c = 0; c < 2; ++c) {
          st[c][0] = pk2(yr[c][0], yi[c][0]);
          st[c][1] = sw8u(pk2(yr[c][1], yi[c][1]));
          st[c][2] = pk2(yr[c][2], yi[c][2]);
          st[c][3] = sw8u(pk2(yr[c][3], yi[c][3]));
        }
      } else {
        // final CNOT on f32, p = |amp|^2 -> LDS p-buffer
        MEMFENCE();
#pragma unroll
        for (int c = 0; c < 2; ++c) {
          float r1 = sw8f(yr[c][1]), i1 = sw8f(yi[c][1]);
          float r3 = sw8f(yr[c][3]), i3 = sw8f(yi[c][3]);
          float p0 = yr[c][0] * yr[c][0] + yi[c][0] * yi[c][0];
          float p1 = r1 * r1 + i1 * i1;
          float p2 = yr[c][2] * yr[c][2] + yi[c][2] * yi[c][2];
          float p3 = r3 * r3 + i3 * i3;
          const unsigned e = (unsigned)(2 * i + c);
          unsigned pOff = e * 512u + ((pWg ^ (e & 7u)) << 4) + pWlo;
          uint2v v = { pk2(p0, p1), pk2(p2, p3) };
          *(uint2v*)(smp + pOff) = v;
        }
        MEMFENCE();
      }
    }
  }

  // ---- measurement: exps(16 elems x 8 qubits) = Sign(16x256) * P(256x16) ----
  float4v acc = zz;
  MEMFENCE();
#pragma unroll
  for (int c = 0; c < 8; ++c) {
    half8 sfv = *(const half8*)(smem + c * 1024 + lane * 16);
    unsigned pR = (unsigned)(n * 512 +
                             ((((unsigned)(c * 4 + quad)) ^ (unsigned)(n & 7)) << 4));
    half8 pbv = *(const half8*)(smp + pR);
    acc = __builtin_amdgcn_mfma_f32_16x16x32_f16(sfv, pbv, acc, 0, 0, 0);
  }
  MEMFENCE();
  // C layout: col = n = element, row = quad*4+reg = qubit (rows 8-15 zero)
  if (quad < 2) {
    float4v* o = (float4v*)(out + (size_t)(e0 + n) * 8 + quad * 4);
    *o = acc;
  }
}

extern "C" void kernel_launch(void* const* d_in, const int* in_sizes, int n_in,
                              void* d_out, int out_size, void* d_ws, size_t ws_size,
                              hipStream_t stream) {
  const float* x = (const float*)d_in[0];
  const float* w = (const float*)d_in[1];
  float* out = (float*)d_out;
  qmain<<<dim3(1024), dim3(256), 0, stream>>>(x, w, out);
}